// Round 1
// baseline (433.926 us; speedup 1.0000x reference)
//
#include <hip/hip_runtime.h>
#include <hip/hip_bf16.h>
#include <math.h>

#define BB 8
#define NN 1024
#define F_IN 384
#define F_HID 96
#define HEADS 8
#define F_OUT 384
#define ROWS (BB*NN)                 // 8192
#define H_DIM (HEADS*F_HID + F_IN)   // 1152
#define OUT_DIM (F_OUT + H_DIM)      // 1536
#define NEG_SLOPE 0.01f
#define LN_EPS 1e-5f

// ---------------- Kernel A: LN(X) -> V = Hn@Wv+bv, Q = V@Wq+bq, K = V@Wk+bk ----
// block: 256 threads = 8 rows x 32 lanes; grid: ROWS/8 = 1024
__global__ __launch_bounds__(256) void kA(const float* __restrict__ X,
                                          const float* __restrict__ Wv, const float* __restrict__ bv,
                                          const float* __restrict__ Wq, const float* __restrict__ bq,
                                          const float* __restrict__ Wk, const float* __restrict__ bk,
                                          float* __restrict__ Vw, float* __restrict__ Qw,
                                          float* __restrict__ Kw) {
    __shared__ float xn[8][F_IN];     // 12 KB
    __shared__ float vsh[8][F_HID];   // 3 KB
    const int t = threadIdx.x;
    const int r = t >> 5, lane = t & 31;
    const int row0 = blockIdx.x * 8;
    const int row = row0 + r;

    // ---- LayerNorm over F_IN=384 ----
    const float4* xrow = (const float4*)(X + (size_t)row * F_IN);
    float4 xv[3];
    float s = 0.f, sq = 0.f;
#pragma unroll
    for (int k = 0; k < 3; ++k) {
        xv[k] = xrow[lane + 32*k];
        s  += xv[k].x + xv[k].y + xv[k].z + xv[k].w;
        sq += xv[k].x*xv[k].x + xv[k].y*xv[k].y + xv[k].z*xv[k].z + xv[k].w*xv[k].w;
    }
#pragma unroll
    for (int m = 1; m < 32; m <<= 1) { s += __shfl_xor(s, m, 32); sq += __shfl_xor(sq, m, 32); }
    const float mu  = s * (1.f/F_IN);
    const float var = sq * (1.f/F_IN) - mu*mu;
    const float rstd = rsqrtf(var + LN_EPS);
    float4* xnr = (float4*)xn[r];
#pragma unroll
    for (int k = 0; k < 3; ++k) {
        float4 o;
        o.x = (xv[k].x - mu) * rstd; o.y = (xv[k].y - mu) * rstd;
        o.z = (xv[k].z - mu) * rstd; o.w = (xv[k].w - mu) * rstd;
        xnr[lane + 32*k] = o;
    }
    __syncthreads();

    // ---- V matvec: j = lane + 32c ----
    float acc[3];
#pragma unroll
    for (int c = 0; c < 3; ++c) acc[c] = bv[lane + 32*c];
    for (int f = 0; f < F_IN; ++f) {
        const float xvv = xn[r][f];
        const float* wrow = Wv + (size_t)f * F_HID + lane;
#pragma unroll
        for (int c = 0; c < 3; ++c) acc[c] = fmaf(xvv, wrow[32*c], acc[c]);
    }
#pragma unroll
    for (int c = 0; c < 3; ++c) {
        Vw[(size_t)row * F_HID + lane + 32*c] = acc[c];
        vsh[r][lane + 32*c] = acc[c];
    }
    __syncthreads();

    // ---- Q, K: 96 -> 8 per row ----
    if (t < 128) {
        const int rr = (t >> 3) & 7;
        const int h  = t & 7;
        const bool isQ = (t < 64);
        const float* Wx = isQ ? Wq : Wk;
        float a = isQ ? bq[h] : bk[h];
#pragma unroll 8
        for (int j = 0; j < F_HID; ++j) a = fmaf(vsh[rr][j], Wx[j*HEADS + h], a);
        const int rowx = row0 + rr;
        if (isQ) Qw[(size_t)rowx * HEADS + h] = a;
        else     Kw[(size_t)rowx * HEADS + h] = a;
    }
}

// ---------------- Kernel B: fused head-softmax attention ----------------
// A[b,i,j,h] = softmax_h(lrelu(Q[b,i,h]*K[b,j,h])); Hh[b,i,h,f] = sum_j A*V[b,j,f]
// Writes H = [Hh (768) | X (384)] into out columns 384..1536.
// block 256 = 8 i-rows x 32 lanes; grid = BB * NN/8 = 1024
__global__ __launch_bounds__(256) void kB(const float* __restrict__ X,
                                          const float* __restrict__ Vw,
                                          const float* __restrict__ Qw,
                                          const float* __restrict__ Kw,
                                          float* __restrict__ out) {
    __shared__ float q_sh[8][HEADS];        // 256 B
    __shared__ float k_sh[32][HEADS];       // 1 KB
    __shared__ float v_sh[32][F_HID];       // 12 KB
    __shared__ float w_sh[8][32][HEADS];    // 8 KB
    const int t = threadIdx.x;
    const int b  = blockIdx.x >> 7;
    const int i0 = (blockIdx.x & 127) * 8;
    const int r = t >> 5, lane = t & 31;

    if (t < 64) ((float*)q_sh)[t] = Qw[(size_t)(b*NN + i0)*HEADS + t];

    float acc[HEADS][3];
#pragma unroll
    for (int h = 0; h < HEADS; ++h)
#pragma unroll
        for (int c = 0; c < 3; ++c) acc[h][c] = 0.f;
    __syncthreads();

    float qv[HEADS];
#pragma unroll
    for (int h = 0; h < HEADS; ++h) qv[h] = q_sh[r][h];

    for (int ch = 0; ch < NN/32; ++ch) {
        const int j0 = ch * 32;
        // stage K chunk: 32*8 = 256 floats
        ((float*)k_sh)[t] = Kw[(size_t)(b*NN + j0)*HEADS + t];
        // stage V chunk: 32*96 floats = 768 float4
        const float4* vg = (const float4*)(Vw + (size_t)(b*NN + j0)*F_HID);
        float4* vl = (float4*)v_sh;
#pragma unroll
        for (int u = t; u < 768; u += 256) vl[u] = vg[u];
        __syncthreads();

        // one (r, jj) softmax per thread; r matches this thread's accumulation row
        {
            const int jj = lane;
            float p[HEADS];
            float m = -1e30f;
#pragma unroll
            for (int h = 0; h < HEADS; ++h) {
                float x = qv[h] * k_sh[jj][h];
                x = (x >= 0.f) ? x : NEG_SLOPE * x;
                p[h] = x;
                m = fmaxf(m, x);
            }
            float sum = 0.f;
#pragma unroll
            for (int h = 0; h < HEADS; ++h) { p[h] = __expf(p[h] - m); sum += p[h]; }
            const float inv = 1.f / sum;
#pragma unroll
            for (int h = 0; h < HEADS; ++h) w_sh[r][jj][h] = p[h] * inv;
        }
        __syncthreads();

        // accumulate: 24 FMAs per jj per thread, 5 LDS reads (2 b128 broadcast + 3 b32)
#pragma unroll 4
        for (int jj = 0; jj < 32; ++jj) {
            const float4 wA = ((const float4*)w_sh[r][jj])[0];
            const float4 wB = ((const float4*)w_sh[r][jj])[1];
            const float wv[8] = {wA.x, wA.y, wA.z, wA.w, wB.x, wB.y, wB.z, wB.w};
            const float vv[3] = {v_sh[jj][lane], v_sh[jj][lane+32], v_sh[jj][lane+64]};
#pragma unroll
            for (int h = 0; h < HEADS; ++h)
#pragma unroll
                for (int c = 0; c < 3; ++c) acc[h][c] = fmaf(wv[h], vv[c], acc[h][c]);
        }
        __syncthreads();
    }

    // write Hh into out cols [384 .. 384+768)
    const int row = b*NN + i0 + r;
    float* orow = out + (size_t)row * OUT_DIM + F_OUT;
#pragma unroll
    for (int h = 0; h < HEADS; ++h)
#pragma unroll
        for (int c = 0; c < 3; ++c) orow[h*F_HID + lane + 32*c] = acc[h][c];

    // passthrough X into out cols [1152 .. 1536)
    for (int u = t; u < 8*F_IN; u += 256) {
        const int rr = u / F_IN, f = u % F_IN;
        out[(size_t)(b*NN + i0 + rr) * OUT_DIM + F_OUT + HEADS*F_HID + f] =
            X[(size_t)(b*NN + i0 + rr) * F_IN + f];
    }
}

// ---------------- Kernel C: O = lrelu(LN(H) @ Wm + bm) into out cols 0..384 ----
// block 256 = 8 groups x 32 lanes; group g computes rows (row0+g, row0+g+8), 12 cols/lane
// grid = ROWS/16 = 512
__global__ __launch_bounds__(256) void kC(const float* __restrict__ Wm,
                                          const float* __restrict__ bm,
                                          float* __restrict__ out) {
    __shared__ float wm_sh[16][F_OUT];   // 24 KB: 16 f-rows of Wm
    __shared__ float hn_sh[16][16];      // 1 KB: 16 rows x 16 f of normalized H
    __shared__ float mu_sh[16], rs_sh[16];
    const int t = threadIdx.x;
    const int row0 = blockIdx.x * 16;

    // phase 0: LN stats over H_DIM=1152 (16 lanes per row)
    {
        const int r = t >> 4, l16 = t & 15;
        const float4* hrow = (const float4*)(out + (size_t)(row0 + r)*OUT_DIM + F_OUT);
        float s = 0.f, sq = 0.f;
#pragma unroll
        for (int k = 0; k < 18; ++k) {
            float4 v = hrow[l16 + 16*k];
            s  += v.x + v.y + v.z + v.w;
            sq += v.x*v.x + v.y*v.y + v.z*v.z + v.w*v.w;
        }
#pragma unroll
        for (int m = 1; m < 16; m <<= 1) { s += __shfl_xor(s, m, 16); sq += __shfl_xor(sq, m, 16); }
        if (l16 == 0) {
            const float mu = s * (1.f/H_DIM);
            const float var = sq * (1.f/H_DIM) - mu*mu;
            mu_sh[r] = mu; rs_sh[r] = rsqrtf(var + LN_EPS);
        }
    }
    __syncthreads();

    const int g = t >> 5, lane = t & 31;
    const int r0 = g, r1 = g + 8;
    float acc0[12], acc1[12];
#pragma unroll
    for (int k = 0; k < 12; ++k) { acc0[k] = 0.f; acc1[k] = 0.f; }

    for (int fc = 0; fc < H_DIM; fc += 16) {
        // stage 16 rows of Wm: 16*384 floats = 1536 float4
        const float4* wg = (const float4*)(Wm + (size_t)fc * F_OUT);
        float4* wl = (float4*)wm_sh;
#pragma unroll
        for (int u = t; u < 1536; u += 256) wl[u] = wg[u];
        // stage normalized H chunk: 16 rows x 16 f
        {
            const int rr = t >> 4, ff = t & 15;
            const float hv = out[(size_t)(row0 + rr)*OUT_DIM + F_OUT + fc + ff];
            hn_sh[rr][ff] = (hv - mu_sh[rr]) * rs_sh[rr];
        }
        __syncthreads();
#pragma unroll
        for (int ff = 0; ff < 16; ++ff) {
            const float h0 = hn_sh[r0][ff];
            const float h1 = hn_sh[r1][ff];
            const float4* wrow = (const float4*)(wm_sh[ff] + lane*12);
            const float4 w0 = wrow[0], w1 = wrow[1], w2 = wrow[2];
            const float wv[12] = {w0.x,w0.y,w0.z,w0.w, w1.x,w1.y,w1.z,w1.w, w2.x,w2.y,w2.z,w2.w};
#pragma unroll
            for (int k = 0; k < 12; ++k) {
                acc0[k] = fmaf(h0, wv[k], acc0[k]);
                acc1[k] = fmaf(h1, wv[k], acc1[k]);
            }
        }
        __syncthreads();
    }

    // epilogue: bias + leaky relu, write O
    const int c0 = lane * 12;
#pragma unroll
    for (int k = 0; k < 12; ++k) {
        const float bmk = bm[c0 + k];
        float o0 = acc0[k] + bmk; o0 = (o0 >= 0.f) ? o0 : NEG_SLOPE * o0;
        float o1 = acc1[k] + bmk; o1 = (o1 >= 0.f) ? o1 : NEG_SLOPE * o1;
        out[(size_t)(row0 + r0)*OUT_DIM + c0 + k] = o0;
        out[(size_t)(row0 + r1)*OUT_DIM + c0 + k] = o1;
    }
}

extern "C" void kernel_launch(void* const* d_in, const int* in_sizes, int n_in,
                              void* d_out, int out_size, void* d_ws, size_t ws_size,
                              hipStream_t stream) {
    const float* X  = (const float*)d_in[0];
    const float* Wv = (const float*)d_in[1];
    const float* bv = (const float*)d_in[2];
    const float* Wq = (const float*)d_in[3];
    const float* bq = (const float*)d_in[4];
    const float* Wk = (const float*)d_in[5];
    const float* bk = (const float*)d_in[6];
    const float* Wm = (const float*)d_in[7];
    const float* bm = (const float*)d_in[8];
    float* out = (float*)d_out;

    float* Vw = (float*)d_ws;                 // ROWS*F_HID
    float* Qw = Vw + (size_t)ROWS * F_HID;    // ROWS*HEADS
    float* Kw = Qw + (size_t)ROWS * HEADS;    // ROWS*HEADS

    kA<<<ROWS/8, 256, 0, stream>>>(X, Wv, bv, Wq, bq, Wk, bk, Vw, Qw, Kw);
    kB<<<BB*(NN/8), 256, 0, stream>>>(X, Vw, Qw, Kw, out);
    kC<<<ROWS/16, 256, 0, stream>>>(Wm, bm, out);
}

// Round 2
// 157.947 us; speedup vs baseline: 2.7473x; 2.7473x over previous
//
#include <hip/hip_runtime.h>
#include <hip/hip_bf16.h>
#include <math.h>

#define BB 8
#define NN 1024
#define F_IN 384
#define F_HID 96
#define HEADS 8
#define F_OUT 384
#define ROWS (BB*NN)                 // 8192
#define H_DIM 1152                   // HEADS*F_HID + F_IN
#define OUT_DIM 1536                 // F_OUT + H_DIM
#define NEG 0.01f
#define LN_EPS 1e-5f

typedef __bf16 bf16x8 __attribute__((ext_vector_type(8)));
typedef float  f32x4  __attribute__((ext_vector_type(4)));

static __device__ __forceinline__ unsigned short b16u(float x) {
    union { __bf16 h; unsigned short u; } c; c.h = (__bf16)x; return c.u;
}

// ---------------- kW: WmT[n][k] = bf16(Wm[k][n]) ----------------
// grid 432 = 36 k-tiles x 12 n-tiles, 32x32 LDS transpose
__global__ __launch_bounds__(256) void kW(const float* __restrict__ Wm,
                                          unsigned short* __restrict__ WmT) {
    __shared__ float tile[32][33];
    const int t = threadIdx.x;
    const int k0 = (blockIdx.x / 12) * 32, n0 = (blockIdx.x % 12) * 32;
#pragma unroll
    for (int p = 0; p < 4; ++p) {
        const int e = t + 256*p, kk = e >> 5, nn = e & 31;
        tile[kk][nn] = Wm[(size_t)(k0 + kk) * F_OUT + n0 + nn];
    }
    __syncthreads();
#pragma unroll
    for (int p = 0; p < 4; ++p) {
        const int e = t + 256*p, nn = e >> 5, kk = e & 31;
        WmT[(size_t)(n0 + nn) * H_DIM + k0 + kk] = b16u(tile[kk][nn]);
    }
}

// ---------------- kA: LN(X) -> V (LDS) -> VT bf16, Q, K ----------------
// block 256 = 8 rows x 32 lanes; grid ROWS/8 = 1024
__global__ __launch_bounds__(256) void kA(const float* __restrict__ X,
                                          const float* __restrict__ Wv, const float* __restrict__ bv,
                                          const float* __restrict__ Wq, const float* __restrict__ bq,
                                          const float* __restrict__ Wk, const float* __restrict__ bk,
                                          unsigned short* __restrict__ VT,
                                          float* __restrict__ Qw, float* __restrict__ Kw) {
    __shared__ float xn[8][F_IN];
    __shared__ float vsh[8][F_HID];
    const int t = threadIdx.x, r = t >> 5, lane = t & 31;
    const int row0 = blockIdx.x * 8, row = row0 + r;
    const int b = row0 >> 10, i_in = row0 & 1023;

    const float4* xrow = (const float4*)(X + (size_t)row * F_IN);
    float4 xv[3];
    float s = 0.f, sq = 0.f;
#pragma unroll
    for (int k = 0; k < 3; ++k) {
        xv[k] = xrow[lane + 32*k];
        s  += xv[k].x + xv[k].y + xv[k].z + xv[k].w;
        sq += xv[k].x*xv[k].x + xv[k].y*xv[k].y + xv[k].z*xv[k].z + xv[k].w*xv[k].w;
    }
#pragma unroll
    for (int m = 1; m < 32; m <<= 1) { s += __shfl_xor(s, m); sq += __shfl_xor(sq, m); }
    const float mu  = s * (1.f/F_IN);
    const float var = sq * (1.f/F_IN) - mu*mu;
    const float rstd = rsqrtf(var + LN_EPS);
    float4* xnr = (float4*)xn[r];
#pragma unroll
    for (int k = 0; k < 3; ++k) {
        float4 o;
        o.x = (xv[k].x - mu) * rstd; o.y = (xv[k].y - mu) * rstd;
        o.z = (xv[k].z - mu) * rstd; o.w = (xv[k].w - mu) * rstd;
        xnr[lane + 32*k] = o;
    }
    __syncthreads();

    float acc[3];
#pragma unroll
    for (int c = 0; c < 3; ++c) acc[c] = bv[lane + 32*c];
    for (int f = 0; f < F_IN; ++f) {
        const float xvv = xn[r][f];
        const float* wrow = Wv + (size_t)f * F_HID + lane;
#pragma unroll
        for (int c = 0; c < 3; ++c) acc[c] = fmaf(xvv, wrow[32*c], acc[c]);
    }
#pragma unroll
    for (int c = 0; c < 3; ++c) vsh[r][lane + 32*c] = acc[c];
    __syncthreads();

    // VT[b][f][i] bf16, coalesced 8-wide in i
#pragma unroll
    for (int p = 0; p < 3; ++p) {
        const int e = t + 256*p, f = e >> 3, ii = e & 7;
        VT[((size_t)b * F_HID + f) * NN + i_in + ii] = b16u(vsh[ii][f]);
    }

    // Q, K
    if (t < 128) {
        const int rr = (t >> 3) & 7, h = t & 7;
        const bool isQ = (t < 64);
        const float* Wx = isQ ? Wq : Wk;
        float a = isQ ? bq[h] : bk[h];
#pragma unroll 8
        for (int j = 0; j < F_HID; ++j) a = fmaf(vsh[rr][j], Wx[j*HEADS + h], a);
        const size_t rowx = row0 + rr;
        if (isQ) Qw[rowx * HEADS + h] = a;
        else     Kw[rowx * HEADS + h] = a;
    }
}

// ---------------- kB: MFMA attention + fused LN(H) ----------------
// block 256 = 4 waves; block owns 16 i-rows; wave w owns heads {2w,2w+1}
// grid = BB * NN/16 = 512
__global__ __launch_bounds__(256) void kB(const float* __restrict__ X,
                                          const unsigned short* __restrict__ VT,
                                          const float* __restrict__ Qw,
                                          const float* __restrict__ Kw,
                                          float* __restrict__ out,
                                          unsigned short* __restrict__ Hn) {
    __shared__ float q_sh[16][8];
    __shared__ float k_sh[32][9];                         // pad 9: conflict-free scalar reads
    __shared__ __align__(16) unsigned short Wt[HEADS][16][32];   // 8 KB, A-frags
    __shared__ __align__(16) unsigned short vt_sh[2][F_HID][32]; // 12 KB, B-frags (dbuf)
    __shared__ float lnS[4][16], lnQ2[4][16];
    __shared__ float mu_sh[16], rs_sh[16];

    const int t = threadIdx.x;
    const int b  = blockIdx.x >> 6;
    const int i0 = (blockIdx.x & 63) * 16;
    const int w = t >> 6, l = t & 63, m = l & 15, g = l >> 4;
    const int si = t >> 4, sj = t & 15;   // softmax pair mapping

    if (t < 128) ((float*)q_sh)[t] = Qw[((size_t)(b*NN + i0)) * HEADS + t];

    const f32x4 z4 = {0.f, 0.f, 0.f, 0.f};
    f32x4 acc[2][6];
#pragma unroll
    for (int h = 0; h < 2; ++h)
#pragma unroll
        for (int fb = 0; fb < 6; ++fb) acc[h][fb] = z4;
    __syncthreads();

    float q[8];
#pragma unroll
    for (int h = 0; h < 8; ++h) q[h] = q_sh[si][h];

    const size_t vtbase = (size_t)b * F_HID * NN;

    for (int ch = 0; ch < 32; ++ch) {
        const int j0 = ch * 32, cur = ch & 1;
        // stage K chunk (32 rows x 8)
        k_sh[t >> 3][t & 7] = Kw[((size_t)(b*NN + j0 + (t >> 3))) * HEADS + (t & 7)];
        // stage VT chunk [96][32] bf16
#pragma unroll
        for (int p = 0; p < 3; ++p) {
            const int e = t + 256*p, f = e >> 3, sub = e & 7;
            *(ushort4*)&vt_sh[cur][f][sub*4] =
                *(const ushort4*)(VT + vtbase + (size_t)f * NN + j0 + sub*4);
        }
        __syncthreads();

        // cooperative softmax over heads: pairs (si, 2sj) and (si, 2sj+1)
        {
            const float* kr = k_sh[2*sj];
            float wE[8], wO[8];
            float sE = 0.f, sO = 0.f;
#pragma unroll
            for (int h = 0; h < 8; ++h) {
                float a0 = q[h] * kr[h];     a0 = fmaxf(a0, NEG*a0);
                float a1 = q[h] * kr[9+h];   a1 = fmaxf(a1, NEG*a1);  // row 2sj+1 (pad 9)
                wE[h] = __expf(a0); sE += wE[h];
                wO[h] = __expf(a1); sO += wO[h];
            }
            const float iE = 1.f / sE, iO = 1.f / sO;
#pragma unroll
            for (int h = 0; h < 8; ++h) {
                const unsigned int pk = (unsigned int)b16u(wE[h]*iE)
                                      | ((unsigned int)b16u(wO[h]*iO) << 16);
                ((unsigned int*)Wt)[h*256 + si*16 + sj] = pk;
            }
        }
        __syncthreads();

        // MFMA: A = Wt[h][16i][32j], B = vt_sh[32j][16f] (V^T rows are f)
        const bf16x8 a0 = *(const bf16x8*)&Wt[2*w    ][m][g*8];
        const bf16x8 a1 = *(const bf16x8*)&Wt[2*w + 1][m][g*8];
#pragma unroll
        for (int fb = 0; fb < 6; ++fb) {
            const bf16x8 bv_ = *(const bf16x8*)&vt_sh[cur][fb*16 + m][g*8];
            acc[0][fb] = __builtin_amdgcn_mfma_f32_16x16x32_bf16(a0, bv_, acc[0][fb], 0, 0, 0);
            acc[1][fb] = __builtin_amdgcn_mfma_f32_16x16x32_bf16(a1, bv_, acc[1][fb], 0, 0, 0);
        }
    }

    // ---- fused LN(H): row sums from accs + X ----
    float s[4] = {0,0,0,0}, s2[4] = {0,0,0,0};
#pragma unroll
    for (int h = 0; h < 2; ++h)
#pragma unroll
        for (int fb = 0; fb < 6; ++fb)
#pragma unroll
            for (int r = 0; r < 4; ++r) {
                const float v = acc[h][fb][r];
                s[r] += v; s2[r] += v*v;
            }
#pragma unroll
    for (int msk = 1; msk < 16; msk <<= 1)
#pragma unroll
        for (int r = 0; r < 4; ++r) {
            s[r]  += __shfl_xor(s[r],  msk);
            s2[r] += __shfl_xor(s2[r], msk);
        }
    if (m == 0) {
#pragma unroll
        for (int r = 0; r < 4; ++r) { lnS[w][g*4+r] = s[r]; lnQ2[w][g*4+r] = s2[r]; }
    }
    __syncthreads();

    const int row16 = t >> 4, xl = t & 15;
    const size_t xrow = (size_t)(b*NN + i0 + row16);
    const float4* x4 = (const float4*)(X + xrow * F_IN);
    float4 xs[6];
    float sx = 0.f, sx2 = 0.f;
#pragma unroll
    for (int kk = 0; kk < 6; ++kk) {
        xs[kk] = x4[xl + 16*kk];
        sx  += xs[kk].x + xs[kk].y + xs[kk].z + xs[kk].w;
        sx2 += xs[kk].x*xs[kk].x + xs[kk].y*xs[kk].y + xs[kk].z*xs[kk].z + xs[kk].w*xs[kk].w;
    }
#pragma unroll
    for (int msk = 1; msk < 16; msk <<= 1) { sx += __shfl_xor(sx, msk); sx2 += __shfl_xor(sx2, msk); }
    if (xl == 0) {
        const float tot  = sx  + lnS[0][row16] + lnS[1][row16] + lnS[2][row16] + lnS[3][row16];
        const float tot2 = sx2 + lnQ2[0][row16] + lnQ2[1][row16] + lnQ2[2][row16] + lnQ2[3][row16];
        const float muh = tot * (1.f/H_DIM);
        const float varh = tot2 * (1.f/H_DIM) - muh*muh;
        mu_sh[row16] = muh; rs_sh[row16] = rsqrtf(varh + LN_EPS);
    }
    __syncthreads();

    // Hh: fp32 to out cols [384..1152), bf16-normalized to Hn cols [0..768)
#pragma unroll
    for (int r = 0; r < 4; ++r) {
        const int row = g*4 + r;
        const size_t orow = (size_t)(b*NN + i0 + row);
        const float muh = mu_sh[row], rs = rs_sh[row];
#pragma unroll
        for (int h = 0; h < 2; ++h)
#pragma unroll
            for (int fb = 0; fb < 6; ++fb) {
                const int col = (2*w + h)*F_HID + fb*16 + m;
                const float v = acc[h][fb][r];
                out[orow * OUT_DIM + F_OUT + col] = v;
                Hn[orow * H_DIM + col] = b16u((v - muh) * rs);
            }
    }
    // X: fp32 passthrough to out cols [1152..1536), bf16-normalized to Hn cols [768..1152)
    {
        const float muh = mu_sh[row16], rs = rs_sh[row16];
        float4* oX = (float4*)(out + xrow * OUT_DIM + F_OUT + HEADS*F_HID);
#pragma unroll
        for (int kk = 0; kk < 6; ++kk) {
            oX[xl + 16*kk] = xs[kk];
            ushort4 hh;
            hh.x = b16u((xs[kk].x - muh) * rs);
            hh.y = b16u((xs[kk].y - muh) * rs);
            hh.z = b16u((xs[kk].z - muh) * rs);
            hh.w = b16u((xs[kk].w - muh) * rs);
            *(ushort4*)&Hn[xrow * H_DIM + HEADS*F_HID + 4*(xl + 16*kk)] = hh;
        }
    }
}

// ---------------- kC: O = lrelu(Hn @ Wm + bm), bf16 MFMA GEMM ----------------
// block 256 = 4 waves; block = 32 rows x 384 cols; wave: 16 rows x 192 cols
// grid = ROWS/32 = 256
__global__ __launch_bounds__(256) void kC(const unsigned short* __restrict__ Hn,
                                          const unsigned short* __restrict__ WmT,
                                          const float* __restrict__ bm,
                                          float* __restrict__ out) {
    const int t = threadIdx.x, w = t >> 6, l = t & 63, m = l & 15, g = l >> 4;
    const int i0 = blockIdx.x * 32 + 16 * (w & 1);
    const int n0 = 192 * (w >> 1);

    const f32x4 z4 = {0.f, 0.f, 0.f, 0.f};
    f32x4 acc[12];
#pragma unroll
    for (int fb = 0; fb < 12; ++fb) acc[fb] = z4;

    const unsigned short* Ar = Hn + (size_t)(i0 + m) * H_DIM + g*8;
    for (int k0 = 0; k0 < H_DIM; k0 += 32) {
        const bf16x8 a = *(const bf16x8*)(Ar + k0);
#pragma unroll
        for (int fb = 0; fb < 12; ++fb) {
            const bf16x8 bfr = *(const bf16x8*)(WmT + (size_t)(n0 + fb*16 + m) * H_DIM + k0 + g*8);
            acc[fb] = __builtin_amdgcn_mfma_f32_16x16x32_bf16(a, bfr, acc[fb], 0, 0, 0);
        }
    }
#pragma unroll
    for (int fb = 0; fb < 12; ++fb) {
        const int col = n0 + fb*16 + m;
        const float bmv = bm[col];
#pragma unroll
        for (int r = 0; r < 4; ++r) {
            float o = acc[fb][r] + bmv;
            o = fmaxf(o, NEG * o);
            out[(size_t)(i0 + g*4 + r) * OUT_DIM + col] = o;
        }
    }
}

extern "C" void kernel_launch(void* const* d_in, const int* in_sizes, int n_in,
                              void* d_out, int out_size, void* d_ws, size_t ws_size,
                              hipStream_t stream) {
    const float* X  = (const float*)d_in[0];
    const float* Wv = (const float*)d_in[1];
    const float* bv = (const float*)d_in[2];
    const float* Wq = (const float*)d_in[3];
    const float* bq = (const float*)d_in[4];
    const float* Wk = (const float*)d_in[5];
    const float* bk = (const float*)d_in[6];
    const float* Wm = (const float*)d_in[7];
    const float* bm = (const float*)d_in[8];
    float* out = (float*)d_out;

    // ws layout (~20.9 MB total)
    char* p = (char*)d_ws;
    unsigned short* VT  = (unsigned short*)p;                 p += (size_t)BB*F_HID*NN*2;   // 1.5 MB
    float*          Qw  = (float*)p;                          p += (size_t)ROWS*HEADS*4;    // 256 KB
    float*          Kw  = (float*)p;                          p += (size_t)ROWS*HEADS*4;    // 256 KB
    unsigned short* WmT = (unsigned short*)p;                 p += (size_t)F_OUT*H_DIM*2;   // 864 KB
    unsigned short* Hn  = (unsigned short*)p;                 /* ROWS*H_DIM*2 = 18 MB */
    (void)ws_size; (void)out_size; (void)n_in; (void)in_sizes;

    kW<<<(H_DIM/32)*(F_OUT/32), 256, 0, stream>>>(Wm, WmT);
    kA<<<ROWS/8, 256, 0, stream>>>(X, Wv, bv, Wq, bq, Wk, bk, VT, Qw, Kw);
    kB<<<BB*(NN/16), 256, 0, stream>>>(X, VT, Qw, Kw, out, Hn);
    kC<<<ROWS/32, 256, 0, stream>>>(Hn, WmT, bm, out);
}

// Round 3
// 121.205 us; speedup vs baseline: 3.5801x; 1.3031x over previous
//
#include <hip/hip_runtime.h>
#include <hip/hip_bf16.h>
#include <math.h>

#define BB 8
#define NN 1024
#define F_IN 384
#define F_HID 96
#define HEADS 8
#define F_OUT 384
#define ROWS (BB*NN)                 // 8192
#define H_DIM 1152                   // HEADS*F_HID + F_IN
#define OUT_DIM 1536                 // F_OUT + H_DIM
#define NEG 0.01f
#define LN_EPS 1e-5f

typedef __bf16 bf16x8 __attribute__((ext_vector_type(8)));
typedef float  f32x4  __attribute__((ext_vector_type(4)));

static __device__ __forceinline__ unsigned short b16u(float x) {
    union { __bf16 h; unsigned short u; } c; c.h = (__bf16)x; return c.u;
}

typedef __attribute__((address_space(1))) const unsigned char g1_t;
typedef __attribute__((address_space(3))) unsigned char l3_t;
static __device__ __forceinline__ void gl16(const void* g, void* l) {
    __builtin_amdgcn_global_load_lds((g1_t*)g, (l3_t*)l, 16, 0, 0);
}

// ---------------- kW: WmT[n][k] = bf16(Wm[k][n]) ----------------
__global__ __launch_bounds__(256) void kW(const float* __restrict__ Wm,
                                          unsigned short* __restrict__ WmT) {
    __shared__ float tile[32][33];
    const int t = threadIdx.x;
    const int k0 = (blockIdx.x / 12) * 32, n0 = (blockIdx.x % 12) * 32;
#pragma unroll
    for (int p = 0; p < 4; ++p) {
        const int e = t + 256*p, kk = e >> 5, nn = e & 31;
        tile[kk][nn] = Wm[(size_t)(k0 + kk) * F_OUT + n0 + nn];
    }
    __syncthreads();
#pragma unroll
    for (int p = 0; p < 4; ++p) {
        const int e = t + 256*p, nn = e >> 5, kk = e & 31;
        WmT[(size_t)(n0 + nn) * H_DIM + k0 + kk] = b16u(tile[kk][nn]);
    }
}

// ---------------- kA: LN(X) -> V -> VT bf16, Q, K (unchanged) ----------------
__global__ __launch_bounds__(256) void kA(const float* __restrict__ X,
                                          const float* __restrict__ Wv, const float* __restrict__ bv,
                                          const float* __restrict__ Wq, const float* __restrict__ bq,
                                          const float* __restrict__ Wk, const float* __restrict__ bk,
                                          unsigned short* __restrict__ VT,
                                          float* __restrict__ Qw, float* __restrict__ Kw) {
    __shared__ float xn[8][F_IN];
    __shared__ float vsh[8][F_HID];
    const int t = threadIdx.x, r = t >> 5, lane = t & 31;
    const int row0 = blockIdx.x * 8, row = row0 + r;
    const int b = row0 >> 10, i_in = row0 & 1023;

    const float4* xrow = (const float4*)(X + (size_t)row * F_IN);
    float4 xv[3];
    float s = 0.f, sq = 0.f;
#pragma unroll
    for (int k = 0; k < 3; ++k) {
        xv[k] = xrow[lane + 32*k];
        s  += xv[k].x + xv[k].y + xv[k].z + xv[k].w;
        sq += xv[k].x*xv[k].x + xv[k].y*xv[k].y + xv[k].z*xv[k].z + xv[k].w*xv[k].w;
    }
#pragma unroll
    for (int m = 1; m < 32; m <<= 1) { s += __shfl_xor(s, m); sq += __shfl_xor(sq, m); }
    const float mu  = s * (1.f/F_IN);
    const float var = sq * (1.f/F_IN) - mu*mu;
    const float rstd = rsqrtf(var + LN_EPS);
    float4* xnr = (float4*)xn[r];
#pragma unroll
    for (int k = 0; k < 3; ++k) {
        float4 o;
        o.x = (xv[k].x - mu) * rstd; o.y = (xv[k].y - mu) * rstd;
        o.z = (xv[k].z - mu) * rstd; o.w = (xv[k].w - mu) * rstd;
        xnr[lane + 32*k] = o;
    }
    __syncthreads();

    float acc[3];
#pragma unroll
    for (int c = 0; c < 3; ++c) acc[c] = bv[lane + 32*c];
    for (int f = 0; f < F_IN; ++f) {
        const float xvv = xn[r][f];
        const float* wrow = Wv + (size_t)f * F_HID + lane;
#pragma unroll
        for (int c = 0; c < 3; ++c) acc[c] = fmaf(xvv, wrow[32*c], acc[c]);
    }
#pragma unroll
    for (int c = 0; c < 3; ++c) vsh[r][lane + 32*c] = acc[c];
    __syncthreads();

#pragma unroll
    for (int p = 0; p < 3; ++p) {
        const int e = t + 256*p, f = e >> 3, ii = e & 7;
        VT[((size_t)b * F_HID + f) * NN + i_in + ii] = b16u(vsh[ii][f]);
    }

    if (t < 128) {
        const int rr = (t >> 3) & 7, h = t & 7;
        const bool isQ = (t < 64);
        const float* Wx = isQ ? Wq : Wk;
        float a = isQ ? bq[h] : bk[h];
#pragma unroll 8
        for (int j = 0; j < F_HID; ++j) a = fmaf(vsh[rr][j], Wx[j*HEADS + h], a);
        const size_t rowx = row0 + rr;
        if (isQ) Qw[rowx * HEADS + h] = a;
        else     Kw[rowx * HEADS + h] = a;
    }
}

// ---------------- kB: pipelined MFMA attention + fused LN(H) ----------------
// block 256 = 4 waves; 16 i-rows; wave w owns heads {2w,2w+1}; grid 512
__global__ __launch_bounds__(256) void kB(const float* __restrict__ X,
                                          const unsigned short* __restrict__ VT,
                                          const float* __restrict__ Qw,
                                          const float* __restrict__ Kw,
                                          float* __restrict__ out,
                                          unsigned short* __restrict__ Hn) {
    __shared__ float q_sh[16][8];
    __shared__ float k_sh[2][32][9];
    __shared__ __align__(16) unsigned short Wt[2][HEADS][16][40];   // 20 KB (pad 80B rows)
    __shared__ __align__(16) unsigned short vt_sh[2][F_HID][40];    // 15 KB
    __shared__ float lnS[4][16], lnQ2[4][16];
    __shared__ float mu_sh[16], rs_sh[16];

    const int t = threadIdx.x;
    const int bid = (int)blockIdx.x;
    const int swz = (bid & 7) * 64 + (bid >> 3);   // bijective XCD swizzle (512%8==0)
    const int b  = swz >> 6;                       // each XCD owns one batch b
    const int i0 = (swz & 63) * 16;
    const int w = t >> 6, l = t & 63, m = l & 15, g = l >> 4;
    const int si = t >> 4, sj = t & 15;

    if (t < 128) ((float*)q_sh)[t] = Qw[((size_t)(b*NN + i0)) * HEADS + t];

    const f32x4 z4 = {0.f, 0.f, 0.f, 0.f};
    f32x4 acc[2][6];
#pragma unroll
    for (int h = 0; h < 2; ++h)
#pragma unroll
        for (int fb = 0; fb < 6; ++fb) acc[h][fb] = z4;

    const size_t vtbase = (size_t)b * F_HID * NN;
    const size_t krow   = (size_t)b * NN;

    // prologue: stage chunk 0
    {
        const float kr = Kw[(krow + (t >> 3)) * HEADS + (t & 7)];
        ushort4 vr[3];
#pragma unroll
        for (int p = 0; p < 3; ++p) {
            const int e = t + 256*p, f = e >> 3, sub = e & 7;
            vr[p] = *(const ushort4*)(VT + vtbase + (size_t)f * NN + sub*4);
        }
        k_sh[0][t >> 3][t & 7] = kr;
#pragma unroll
        for (int p = 0; p < 3; ++p) {
            const int e = t + 256*p, f = e >> 3, sub = e & 7;
            *(ushort4*)&vt_sh[0][f][sub*4] = vr[p];
        }
    }
    __syncthreads();

    float q[8];
#pragma unroll
    for (int h = 0; h < 8; ++h) q[h] = q_sh[si][h];

    // softmax(0) -> Wt[0]
    {
        const float* kr0 = k_sh[0][2*sj];
        float wE[8], wO[8];
        float sE = 0.f, sO = 0.f;
#pragma unroll
        for (int h = 0; h < 8; ++h) {
            float a0v = q[h]*kr0[h];   a0v = fmaxf(a0v, NEG*a0v);
            float a1v = q[h]*kr0[9+h]; a1v = fmaxf(a1v, NEG*a1v);
            wE[h] = __expf(a0v); sE += wE[h];
            wO[h] = __expf(a1v); sO += wO[h];
        }
        const float iE = 1.f/sE, iO = 1.f/sO;
#pragma unroll
        for (int h = 0; h < 8; ++h)
            *(unsigned int*)&Wt[0][h][si][2*sj] =
                (unsigned int)b16u(wE[h]*iE) | ((unsigned int)b16u(wO[h]*iO) << 16);
    }
    __syncthreads();

    for (int ch = 0; ch < 32; ++ch) {
        const int cur = ch & 1, nxt = cur ^ 1;
        const bool more = (ch < 31);

        // phase A: issue next chunk's global loads into registers (in flight under MFMA)
        float kr = 0.f; ushort4 vr[3];
        if (more) {
            const int j0n = (ch + 1) * 32;
            kr = Kw[(krow + j0n + (t >> 3)) * HEADS + (t & 7)];
#pragma unroll
            for (int p = 0; p < 3; ++p) {
                const int e = t + 256*p, f = e >> 3, sub = e & 7;
                vr[p] = *(const ushort4*)(VT + vtbase + (size_t)f * NN + j0n + sub*4);
            }
        }

        // phase B: MFMA on current chunk
        const bf16x8 a0 = *(const bf16x8*)&Wt[cur][2*w    ][m][g*8];
        const bf16x8 a1 = *(const bf16x8*)&Wt[cur][2*w + 1][m][g*8];
#pragma unroll
        for (int fb = 0; fb < 6; ++fb) {
            const bf16x8 bv_ = *(const bf16x8*)&vt_sh[cur][fb*16 + m][g*8];
            acc[0][fb] = __builtin_amdgcn_mfma_f32_16x16x32_bf16(a0, bv_, acc[0][fb], 0, 0, 0);
            acc[1][fb] = __builtin_amdgcn_mfma_f32_16x16x32_bf16(a1, bv_, acc[1][fb], 0, 0, 0);
        }

        if (more) {
            // phase C: write staged regs -> LDS[nxt]
            k_sh[nxt][t >> 3][t & 7] = kr;
#pragma unroll
            for (int p = 0; p < 3; ++p) {
                const int e = t + 256*p, f = e >> 3, sub = e & 7;
                *(ushort4*)&vt_sh[nxt][f][sub*4] = vr[p];
            }
            __syncthreads();
            // phase D: softmax(ch+1) -> Wt[nxt]
            {
                const float* kr0 = k_sh[nxt][2*sj];
                float wE[8], wO[8];
                float sE = 0.f, sO = 0.f;
#pragma unroll
                for (int h = 0; h < 8; ++h) {
                    float a0v = q[h]*kr0[h];   a0v = fmaxf(a0v, NEG*a0v);
                    float a1v = q[h]*kr0[9+h]; a1v = fmaxf(a1v, NEG*a1v);
                    wE[h] = __expf(a0v); sE += wE[h];
                    wO[h] = __expf(a1v); sO += wO[h];
                }
                const float iE = 1.f/sE, iO = 1.f/sO;
#pragma unroll
                for (int h = 0; h < 8; ++h)
                    *(unsigned int*)&Wt[nxt][h][si][2*sj] =
                        (unsigned int)b16u(wE[h]*iE) | ((unsigned int)b16u(wO[h]*iO) << 16);
            }
            __syncthreads();
        }
    }

    // ---- fused LN(H) ----
    float s[4] = {0,0,0,0}, s2[4] = {0,0,0,0};
#pragma unroll
    for (int h = 0; h < 2; ++h)
#pragma unroll
        for (int fb = 0; fb < 6; ++fb)
#pragma unroll
            for (int r = 0; r < 4; ++r) {
                const float v = acc[h][fb][r];
                s[r] += v; s2[r] += v*v;
            }
#pragma unroll
    for (int msk = 1; msk < 16; msk <<= 1)
#pragma unroll
        for (int r = 0; r < 4; ++r) {
            s[r]  += __shfl_xor(s[r],  msk);
            s2[r] += __shfl_xor(s2[r], msk);
        }
    if (m == 0) {
#pragma unroll
        for (int r = 0; r < 4; ++r) { lnS[w][g*4+r] = s[r]; lnQ2[w][g*4+r] = s2[r]; }
    }
    __syncthreads();

    const int row16 = t >> 4, xl = t & 15;
    const size_t xrow = (size_t)(b*NN + i0 + row16);
    const float4* x4 = (const float4*)(X + xrow * F_IN);
    float4 xs[6];
    float sx = 0.f, sx2 = 0.f;
#pragma unroll
    for (int kk = 0; kk < 6; ++kk) {
        xs[kk] = x4[xl + 16*kk];
        sx  += xs[kk].x + xs[kk].y + xs[kk].z + xs[kk].w;
        sx2 += xs[kk].x*xs[kk].x + xs[kk].y*xs[kk].y + xs[kk].z*xs[kk].z + xs[kk].w*xs[kk].w;
    }
#pragma unroll
    for (int msk = 1; msk < 16; msk <<= 1) { sx += __shfl_xor(sx, msk); sx2 += __shfl_xor(sx2, msk); }
    if (xl == 0) {
        const float tot  = sx  + lnS[0][row16] + lnS[1][row16] + lnS[2][row16] + lnS[3][row16];
        const float tot2 = sx2 + lnQ2[0][row16] + lnQ2[1][row16] + lnQ2[2][row16] + lnQ2[3][row16];
        const float muh = tot * (1.f/H_DIM);
        const float varh = tot2 * (1.f/H_DIM) - muh*muh;
        mu_sh[row16] = muh; rs_sh[row16] = rsqrtf(varh + LN_EPS);
    }
    __syncthreads();

#pragma unroll
    for (int r = 0; r < 4; ++r) {
        const int row = g*4 + r;
        const size_t orow = (size_t)(b*NN + i0 + row);
        const float muh = mu_sh[row], rs = rs_sh[row];
#pragma unroll
        for (int h = 0; h < 2; ++h)
#pragma unroll
            for (int fb = 0; fb < 6; ++fb) {
                const int col = (2*w + h)*F_HID + fb*16 + m;
                const float v = acc[h][fb][r];
                out[orow * OUT_DIM + F_OUT + col] = v;
                Hn[orow * H_DIM + col] = b16u((v - muh) * rs);
            }
    }
    {
        const float muh = mu_sh[row16], rs = rs_sh[row16];
        float4* oX = (float4*)(out + xrow * OUT_DIM + F_OUT + HEADS*F_HID);
#pragma unroll
        for (int kk = 0; kk < 6; ++kk) {
            oX[xl + 16*kk] = xs[kk];
            ushort4 hh;
            hh.x = b16u((xs[kk].x - muh) * rs);
            hh.y = b16u((xs[kk].y - muh) * rs);
            hh.z = b16u((xs[kk].z - muh) * rs);
            hh.w = b16u((xs[kk].w - muh) * rs);
            *(ushort4*)&Hn[xrow * H_DIM + HEADS*F_HID + 4*(xl + 16*kk)] = hh;
        }
    }
}

// ---------------- kC: O = lrelu(Hn @ WmT^T + bm), tiled MFMA GEMM ----------------
// BM=64 BN=96 BK=64; grid 512 (2 blocks/CU); 4 waves, wave = 32M x 48N
// LDS dbuf via global_load_lds(16B), XOR-swizzled tiles (T2, rule 21)
__global__ __launch_bounds__(256) void kC(const unsigned short* __restrict__ Hn,
                                          const unsigned short* __restrict__ WmT,
                                          const float* __restrict__ bm,
                                          float* __restrict__ out) {
    __shared__ __align__(16) unsigned short As[2][64*64];   // 16 KB
    __shared__ __align__(16) unsigned short Bs[2][96*64];   // 24 KB
    const int t = threadIdx.x, w = t >> 6, lane = t & 63, m = lane & 15, g = lane >> 4;
    const int bid = (int)blockIdx.x;
    const int swz = (bid & 7) * 64 + (bid >> 3);   // bijective XCD swizzle
    const int i0 = (swz >> 2) * 64;
    const int n0 = (swz & 3) * 96;
    const int wr = w >> 1, wc = w & 1;

    const f32x4 z4 = {0.f, 0.f, 0.f, 0.f};
    f32x4 acc[2][3];
#pragma unroll
    for (int ms = 0; ms < 2; ++ms)
#pragma unroll
        for (int ns = 0; ns < 3; ++ns) acc[ms][ns] = z4;

    // stage one BK=64 tile: linear LDS dest, inverse-swizzled global source
#define KC_STAGE(buf, k0)                                                              \
    {                                                                                  \
        _Pragma("unroll")                                                              \
        for (int p = 0; p < 2; ++p) {                                                  \
            const int e = t + 256*p, row = e >> 3, c16 = e & 7;                        \
            gl16(Hn + (size_t)(i0+row)*H_DIM + (k0) + ((c16 ^ (row&7)) << 3),          \
                 (char*)As[buf] + e*16);                                               \
        }                                                                              \
        _Pragma("unroll")                                                              \
        for (int p = 0; p < 3; ++p) {                                                  \
            const int e = t + 256*p, row = e >> 3, c16 = e & 7;                        \
            gl16(WmT + (size_t)(n0+row)*H_DIM + (k0) + ((c16 ^ (row&7)) << 3),         \
                 (char*)Bs[buf] + e*16);                                               \
        }                                                                              \
    }

    KC_STAGE(0, 0);
    __syncthreads();

    for (int s = 0; s < 18; ++s) {
        const int cur = s & 1;
        if (s < 17) KC_STAGE(cur ^ 1, (s + 1) * 64);
#pragma unroll
        for (int kh = 0; kh < 2; ++kh) {
            const int kb = kh*64 + g*16;
            bf16x8 af[2];
#pragma unroll
            for (int ms = 0; ms < 2; ++ms) {
                const int row = wr*32 + ms*16 + m;
                af[ms] = *(const bf16x8*)((const char*)As[cur] + row*128 + (kb ^ ((row&7)<<4)));
            }
#pragma unroll
            for (int ns = 0; ns < 3; ++ns) {
                const int row = wc*48 + ns*16 + m;
                const bf16x8 bf_ = *(const bf16x8*)((const char*)Bs[cur] + row*128 + (kb ^ ((row&7)<<4)));
                acc[0][ns] = __builtin_amdgcn_mfma_f32_16x16x32_bf16(af[0], bf_, acc[0][ns], 0, 0, 0);
                acc[1][ns] = __builtin_amdgcn_mfma_f32_16x16x32_bf16(af[1], bf_, acc[1][ns], 0, 0, 0);
            }
        }
        __syncthreads();   // drains vmcnt (gload_lds) + lgkm before buffer swap
    }
#undef KC_STAGE

#pragma unroll
    for (int ms = 0; ms < 2; ++ms)
#pragma unroll
        for (int ns = 0; ns < 3; ++ns) {
            const int col = n0 + wc*48 + ns*16 + m;
            const float bmv = bm[col];
#pragma unroll
            for (int r = 0; r < 4; ++r) {
                float o = acc[ms][ns][r] + bmv;
                o = fmaxf(o, NEG * o);
                out[(size_t)(i0 + wr*32 + ms*16 + g*4 + r) * OUT_DIM + col] = o;
            }
        }
}

extern "C" void kernel_launch(void* const* d_in, const int* in_sizes, int n_in,
                              void* d_out, int out_size, void* d_ws, size_t ws_size,
                              hipStream_t stream) {
    const float* X  = (const float*)d_in[0];
    const float* Wv = (const float*)d_in[1];
    const float* bv = (const float*)d_in[2];
    const float* Wq = (const float*)d_in[3];
    const float* bq = (const float*)d_in[4];
    const float* Wk = (const float*)d_in[5];
    const float* bk = (const float*)d_in[6];
    const float* Wm = (const float*)d_in[7];
    const float* bm = (const float*)d_in[8];
    float* out = (float*)d_out;

    char* p = (char*)d_ws;
    unsigned short* VT  = (unsigned short*)p;                 p += (size_t)BB*F_HID*NN*2;
    float*          Qw  = (float*)p;                          p += (size_t)ROWS*HEADS*4;
    float*          Kw  = (float*)p;                          p += (size_t)ROWS*HEADS*4;
    unsigned short* WmT = (unsigned short*)p;                 p += (size_t)F_OUT*H_DIM*2;
    unsigned short* Hn  = (unsigned short*)p;
    (void)ws_size; (void)out_size; (void)n_in; (void)in_sizes;

    kW<<<(H_DIM/32)*(F_OUT/32), 256, 0, stream>>>(Wm, WmT);
    kA<<<ROWS/8, 256, 0, stream>>>(X, Wv, bv, Wq, bq, Wk, bk, VT, Qw, Kw);
    kB<<<BB*(NN/16), 256, 0, stream>>>(X, VT, Qw, Kw, out, Hn);
    kC<<<ROWS/64 * (F_OUT/96), 256, 0, stream>>>(Hn, WmT, bm, out);
}